// Round 3
// baseline (338.885 us; speedup 1.0000x reference)
//
#include <hip/hip_runtime.h>
#include <hip/hip_bf16.h>

// Problem: B=8, C=192, N=3136, K=9, COUT=384.
// out[b,o,n] = relu( bias[o] + max_k( u[b,i1,o] + v[b,i0,o] ) )
//   u = (W1-W2)·xs,  v = W2·xs   (per-node GEMMs; 9x less compute than per-edge)
// Dtype-adaptive: detect kernel decides fp32-vs-bf16 floats and int64-vs-int32
// indices at runtime; all kernels branch uniformly on flags in ws.
// ws layout: flags @0 (64B) | A_T fp32 @1KB (590KB) | U bf16 @1MB | V bf16 (total ~39.6MB)

#define Bb   8
#define Cc   192
#define Nn   3136
#define Kk   9
#define CO   384
#define TWOC 384   // 2*C
#define JTOT 768   // 2*COUT

__device__ __forceinline__ float bf2f(unsigned int u16) {
    union { unsigned int i; float f; } c;
    c.i = u16 << 16;
    return c.f;
}

// ---------------- detect: decide input dtypes ----------------
__global__ __launch_bounds__(256) void detect(const unsigned short* __restrict__ xu,
                                              const int* __restrict__ ei,
                                              int* __restrict__ flags) {
    __shared__ int s_badf;   // bf16 inf/nan bit patterns seen in x
    __shared__ int s_odd;    // nonzero odd int32 words seen in edge_index
    if (threadIdx.x == 0) { s_badf = 0; s_odd = 0; }
    __syncthreads();
    int badf = 0;
    // 64K ushorts = 128KB; smallest possible x buffer (bf16) is 9.6MB — in bounds.
    for (int i = threadIdx.x; i < 65536; i += 256) {
        unsigned int e = (xu[i] >> 7) & 0xFFu;
        badf += (e == 0xFFu);
    }
    int odd = 0;
    // 2048 int64-candidate slots = 16KB; smallest ei buffer (int32) is 1.77MB — in bounds.
    for (int i = threadIdx.x; i < 2048; i += 256) {
        odd += (ei[2 * i + 1] != 0);
    }
    atomicAdd(&s_badf, badf);
    atomicAdd(&s_odd, odd);
    __syncthreads();
    if (threadIdx.x == 0) {
        flags[0] = (s_badf > 0) ? 1 : 0;   // 1 => floats are fp32
        flags[1] = (s_odd == 0) ? 1 : 0;   // 1 => indices are int64
    }
}

// ---------------- prep: A_T[c][j] = (j<384 ? W[j][c]-W[j][C+c] : W[j-384][C+c]) ----------------
__global__ __launch_bounds__(256) void prep_AT(const void* __restrict__ W_,
                                               float* __restrict__ A_T,
                                               const int* __restrict__ flags) {
    const int fp32 = flags[0];
    int t = blockIdx.x * 256 + threadIdx.x;
    if (t >= Cc * JTOT) return;
    int c = t / JTOT;
    int j = t % JTOT;
    int row = (j < CO) ? j : (j - CO);
    float w1, w2;
    if (fp32) {
        const float* W = (const float*)W_;
        w1 = W[row * TWOC + c];
        w2 = W[row * TWOC + Cc + c];
    } else {
        const unsigned short* W = (const unsigned short*)W_;
        w1 = bf2f(W[row * TWOC + c]);
        w2 = bf2f(W[row * TWOC + Cc + c]);
    }
    A_T[t] = (j < CO) ? (w1 - w2) : w2;
}

// ---------------- GEMM: T[b][n][j] = sum_c xs[b][c][n] * A_T[c][j] ----------------
#define TN 64
#define TJ 64
#define TK 16

__global__ __launch_bounds__(256) void gemm_uv(const void* __restrict__ x_,
                                               const float* __restrict__ A_T,
                                               __hip_bfloat16* __restrict__ U,
                                               __hip_bfloat16* __restrict__ V,
                                               const int* __restrict__ flags) {
    __shared__ float xs[TK][TN];
    __shared__ float at[TK][TJ];

    const int fp32 = flags[0];
    const int n0 = blockIdx.x * TN;
    const int j0 = blockIdx.y * TJ;
    const int b  = blockIdx.z;
    const int t  = threadIdx.x;
    const int r  = t >> 4;   // 0..15
    const int q  = t & 15;   // 0..15

    float acc[4][4] = {};

    for (int c0 = 0; c0 < Cc; c0 += TK) {
        if (fp32) {
            const float* xb = (const float*)x_ + (size_t)b * Cc * Nn;
            const float4 xv4 = *reinterpret_cast<const float4*>(
                xb + (size_t)(c0 + r) * Nn + n0 + q * 4);
            *reinterpret_cast<float4*>(&xs[r][q * 4]) = xv4;
        } else {
            const unsigned short* xb = (const unsigned short*)x_ + (size_t)b * Cc * Nn;
            const ushort4 xv4 = *reinterpret_cast<const ushort4*>(
                xb + (size_t)(c0 + r) * Nn + n0 + q * 4);
            xs[r][q * 4 + 0] = bf2f(xv4.x);
            xs[r][q * 4 + 1] = bf2f(xv4.y);
            xs[r][q * 4 + 2] = bf2f(xv4.z);
            xs[r][q * 4 + 3] = bf2f(xv4.w);
        }
        {
            const float4 pa4 = *reinterpret_cast<const float4*>(
                A_T + (size_t)(c0 + r) * JTOT + j0 + q * 4);
            *reinterpret_cast<float4*>(&at[r][q * 4]) = pa4;
        }
        __syncthreads();

#pragma unroll
        for (int c = 0; c < TK; ++c) {
            float4 xv = *(const float4*)&xs[c][r * 4];
            float4 av = *(const float4*)&at[c][q * 4];
            acc[0][0] += xv.x * av.x;  acc[0][1] += xv.x * av.y;
            acc[0][2] += xv.x * av.z;  acc[0][3] += xv.x * av.w;
            acc[1][0] += xv.y * av.x;  acc[1][1] += xv.y * av.y;
            acc[1][2] += xv.y * av.z;  acc[1][3] += xv.y * av.w;
            acc[2][0] += xv.z * av.x;  acc[2][1] += xv.z * av.y;
            acc[2][2] += xv.z * av.z;  acc[2][3] += xv.z * av.w;
            acc[3][0] += xv.w * av.x;  acc[3][1] += xv.w * av.y;
            acc[3][2] += xv.w * av.z;  acc[3][3] += xv.w * av.w;
        }
        __syncthreads();
    }

#pragma unroll
    for (int i = 0; i < 4; ++i) {
        int n = n0 + r * 4 + i;
        __hip_bfloat16* dst;
        if (j0 < CO) {
            dst = U + ((size_t)(b * Nn + n)) * CO + j0 + q * 4;
        } else {
            dst = V + ((size_t)(b * Nn + n)) * CO + (j0 - CO) + q * 4;
        }
        __hip_bfloat16 t4[4] = { __float2bfloat16(acc[i][0]), __float2bfloat16(acc[i][1]),
                                 __float2bfloat16(acc[i][2]), __float2bfloat16(acc[i][3]) };
        ushort4 pv;
        __builtin_memcpy(&pv, t4, 8);
        *reinterpret_cast<ushort4*>(dst) = pv;
    }
}

// ---------------- gather + max + bias + relu ----------------
// block = (n, b), 192 threads; thread t handles channels o=2t, 2t+1
__global__ __launch_bounds__(192) void gather_max(const int* __restrict__ ei,
                                                  const __hip_bfloat16* __restrict__ U,
                                                  const __hip_bfloat16* __restrict__ V,
                                                  const void* __restrict__ bias_,
                                                  void* __restrict__ out_,
                                                  const int* __restrict__ flags) {
    __shared__ int s_i0[Kk];
    __shared__ int s_i1[Kk];
    const int fp32  = flags[0];
    const int is64  = flags[1];
    const int n = blockIdx.x;
    const int b = blockIdx.y;
    const int t = threadIdx.x;

    if (t < Kk) {
        size_t pos = ((size_t)b * Nn + n) * Kk + t;                 // edge_index[0] (x_j)
        int v = is64 ? ei[2 * pos] : ei[pos];
        s_i0[t] = v < 0 ? 0 : (v >= Nn ? Nn - 1 : v);
    } else if (t < 2 * Kk) {
        size_t pos = ((size_t)(Bb + b) * Nn + n) * Kk + (t - Kk);   // edge_index[1] (x_i)
        int v = is64 ? ei[2 * pos] : ei[pos];
        s_i1[t - Kk] = v < 0 ? 0 : (v >= Nn ? Nn - 1 : v);
    }
    __syncthreads();

    const unsigned short* Ub = (const unsigned short*)U + (size_t)b * Nn * CO;
    const unsigned short* Vb = (const unsigned short*)V + (size_t)b * Nn * CO;

    float m0 = -INFINITY, m1 = -INFINITY;
#pragma unroll
    for (int k = 0; k < Kk; ++k) {
        const unsigned int uu = *reinterpret_cast<const unsigned int*>(Ub + (size_t)s_i1[k] * CO + 2 * t);
        const unsigned int vv = *reinterpret_cast<const unsigned int*>(Vb + (size_t)s_i0[k] * CO + 2 * t);
        m0 = fmaxf(m0, bf2f(uu & 0xffffu) + bf2f(vv & 0xffffu));
        m1 = fmaxf(m1, bf2f(uu >> 16) + bf2f(vv >> 16));
    }
    float b0, b1;
    if (fp32) {
        b0 = ((const float*)bias_)[2 * t];
        b1 = ((const float*)bias_)[2 * t + 1];
    } else {
        b0 = bf2f(((const unsigned short*)bias_)[2 * t]);
        b1 = bf2f(((const unsigned short*)bias_)[2 * t + 1]);
    }
    m0 = fmaxf(m0 + b0, 0.0f);
    m1 = fmaxf(m1 + b1, 0.0f);
    size_t o0 = ((size_t)b * CO + 2 * t) * Nn + n;
    size_t o1 = ((size_t)b * CO + 2 * t + 1) * Nn + n;
    if (fp32) {
        ((float*)out_)[o0] = m0;
        ((float*)out_)[o1] = m1;
    } else {
        ((__hip_bfloat16*)out_)[o0] = __float2bfloat16(m0);
        ((__hip_bfloat16*)out_)[o1] = __float2bfloat16(m1);
    }
}

extern "C" void kernel_launch(void* const* d_in, const int* in_sizes, int n_in,
                              void* d_out, int out_size, void* d_ws, size_t ws_size,
                              hipStream_t stream) {
    const void* x  = d_in[0];
    const int*  ei = (const int*)d_in[1];
    const void* W  = d_in[2];
    const void* bs = d_in[3];

    char* ws = (char*)d_ws;
    int*   flags = (int*)ws;                                     // 64 B
    float* A_T   = (float*)(ws + 1024);                          // 589,824 B
    __hip_bfloat16* U = (__hip_bfloat16*)(ws + (1u << 20));      // 19,267,584 B
    __hip_bfloat16* V = U + (size_t)Bb * Nn * CO;                // 19,267,584 B

    detect<<<1, 256, 0, stream>>>((const unsigned short*)x, ei, flags);

    prep_AT<<<(Cc * JTOT + 255) / 256, 256, 0, stream>>>(W, A_T, flags);

    dim3 g1(Nn / TN, JTOT / TJ, Bb);   // (49, 12, 8)
    gemm_uv<<<g1, 256, 0, stream>>>(x, A_T, U, V, flags);

    dim3 g2(Nn, Bb);                   // (3136, 8)
    gather_max<<<g2, 192, 0, stream>>>(ei, U, V, bs, d_out, flags);
}

// Round 4
// 184.656 us; speedup vs baseline: 1.8352x; 1.8352x over previous
//
#include <hip/hip_runtime.h>
#include <hip/hip_bf16.h>

// B=8, C=192, N=3136, K=9, COUT=384.
// out[b,o,n] = relu( bias[o] + max_k( u[b,i1,o] + v[b,i0,o] ) )
//   u = (W1-W2)·xs,  v = W2·xs   (per-node GEMMs; 9x less compute than per-edge)
// Dtype-adaptive (runtime detect): fp32-vs-bf16 floats, int64-vs-int32 indices.
// ws: flags @0 | A_Tb bf16 [j=768][c=192] @1KB (295KB) | U bf16 @1MB | V bf16 (~39.6MB total)

#define Bb   8
#define Cc   192
#define Nn   3136
#define Kk   9
#define CO   384
#define TWOC 384
#define JTOT 768

typedef short  short8 __attribute__((ext_vector_type(8)));
typedef float  f32x4  __attribute__((ext_vector_type(4)));

__device__ __forceinline__ float bf2f(unsigned int u16) {
    union { unsigned int i; float f; } c;
    c.i = u16 << 16;
    return c.f;
}
__device__ __forceinline__ short f2bf(float f) {
    __hip_bfloat16 h = __float2bfloat16(f);
    short s; __builtin_memcpy(&s, &h, 2); return s;
}

// ---------------- detect input dtypes ----------------
__global__ __launch_bounds__(256) void detect(const unsigned short* __restrict__ xu,
                                              const int* __restrict__ ei,
                                              int* __restrict__ flags) {
    __shared__ int s_badf, s_odd;
    if (threadIdx.x == 0) { s_badf = 0; s_odd = 0; }
    __syncthreads();
    int badf = 0;
    for (int i = threadIdx.x; i < 65536; i += 256)
        badf += (((xu[i] >> 7) & 0xFFu) == 0xFFu);
    int odd = 0;
    for (int i = threadIdx.x; i < 2048; i += 256)
        odd += (ei[2 * i + 1] != 0);
    atomicAdd(&s_badf, badf);
    atomicAdd(&s_odd, odd);
    __syncthreads();
    if (threadIdx.x == 0) {
        flags[0] = (s_badf > 0) ? 1 : 0;   // floats are fp32
        flags[1] = (s_odd == 0) ? 1 : 0;   // indices are int64
    }
}

// ---------------- prep: A_Tb[j][c] bf16; j<384: W1-W2, j>=384: W2 ----------------
__global__ __launch_bounds__(256) void prep_AT(const void* __restrict__ W_,
                                               short* __restrict__ A_Tb,
                                               const int* __restrict__ flags) {
    const int fp32 = flags[0];
    int t = blockIdx.x * 256 + threadIdx.x;
    if (t >= JTOT * Cc) return;
    int j = t / Cc;
    int c = t - j * Cc;
    int row = (j < CO) ? j : (j - CO);
    float w1, w2;
    if (fp32) {
        const float* W = (const float*)W_;
        w1 = W[row * TWOC + c];  w2 = W[row * TWOC + Cc + c];
    } else {
        const unsigned short* W = (const unsigned short*)W_;
        w1 = bf2f(W[row * TWOC + c]);  w2 = bf2f(W[row * TWOC + Cc + c]);
    }
    A_Tb[t] = f2bf((j < CO) ? (w1 - w2) : w2);
}

// ---------------- MFMA GEMM: T[b][n][j] = sum_c xs[b][c][n] * A_T[c][j] ----------------
// tile 64(n) x 128(j), K-step 32; 4 waves: wave w covers j-range [w*32, w*32+32)
#define MT 64
#define NT 128
#define KT 32
#define LPAD 40   // LDS row stride in bf16 elems (32 + 8): 80B rows, 2-way bank alias = free

__global__ __launch_bounds__(256) void gemm_mfma(const void* __restrict__ x_,
                                                 const short* __restrict__ A_Tb,
                                                 short* __restrict__ U,
                                                 short* __restrict__ V,
                                                 const int* __restrict__ flags) {
    __shared__ short Asl[MT * LPAD];   // [n][c]
    __shared__ short Bsl[NT * LPAD];   // [j][c]

    const int fp32 = flags[0];
    const int n0 = blockIdx.x * MT;
    const int j0 = blockIdx.y * NT;
    const int b  = blockIdx.z;
    const int tid  = threadIdx.x;
    const int w    = tid >> 6;
    const int lane = tid & 63;
    const int col  = lane & 15;
    const int quad = lane >> 4;

    f32x4 acc[4][2];
#pragma unroll
    for (int i = 0; i < 4; ++i) { acc[i][0] = (f32x4)(0.0f); acc[i][1] = (f32x4)(0.0f); }

    const int ac   = tid >> 3;   // c-index 0..31 for A staging
    const int aseg = tid & 7;    // n-segment (8 nodes)

    for (int c0 = 0; c0 < Cc; c0 += KT) {
        // stage A: xs[b][c][n] -> Asl[n][c]  (transpose in LDS)
        if (fp32) {
            const float* xb = (const float*)x_ + ((size_t)b * Cc + c0 + ac) * Nn + n0 + aseg * 8;
            float4 v0 = *(const float4*)xb;
            float4 v1 = *(const float4*)(xb + 4);
            int nb = aseg * 8;
            Asl[(nb + 0) * LPAD + ac] = f2bf(v0.x);
            Asl[(nb + 1) * LPAD + ac] = f2bf(v0.y);
            Asl[(nb + 2) * LPAD + ac] = f2bf(v0.z);
            Asl[(nb + 3) * LPAD + ac] = f2bf(v0.w);
            Asl[(nb + 4) * LPAD + ac] = f2bf(v1.x);
            Asl[(nb + 5) * LPAD + ac] = f2bf(v1.y);
            Asl[(nb + 6) * LPAD + ac] = f2bf(v1.z);
            Asl[(nb + 7) * LPAD + ac] = f2bf(v1.w);
        } else {
            const unsigned short* xb = (const unsigned short*)x_ + ((size_t)b * Cc + c0 + ac) * Nn + n0 + aseg * 8;
            ushort4 u0 = *(const ushort4*)xb;
            ushort4 u1 = *(const ushort4*)(xb + 4);
            int nb = aseg * 8;
            Asl[(nb + 0) * LPAD + ac] = (short)u0.x;
            Asl[(nb + 1) * LPAD + ac] = (short)u0.y;
            Asl[(nb + 2) * LPAD + ac] = (short)u0.z;
            Asl[(nb + 3) * LPAD + ac] = (short)u0.w;
            Asl[(nb + 4) * LPAD + ac] = (short)u1.x;
            Asl[(nb + 5) * LPAD + ac] = (short)u1.y;
            Asl[(nb + 6) * LPAD + ac] = (short)u1.z;
            Asl[(nb + 7) * LPAD + ac] = (short)u1.w;
        }
        // stage B: A_Tb[j][c] -> Bsl[j][c]  (straight copy, 16B segments)
        {
            int s0 = tid * 2;
#pragma unroll
            for (int s = s0; s < s0 + 2; ++s) {
                int j = s >> 2, h = s & 3;
                short8 vv = *(const short8*)(A_Tb + (size_t)(j0 + j) * Cc + c0 + h * 8);
                *(short8*)(&Bsl[j * LPAD + h * 8]) = vv;
            }
        }
        __syncthreads();

        // compute: A[m=lane&15][k=quad*8+i], B[k=quad*8+i][n=lane&15], D[row=quad*4+r][col=lane&15]
        short8 bf0 = *(const short8*)(&Bsl[(w * 32 + col) * LPAD + quad * 8]);
        short8 bf1 = *(const short8*)(&Bsl[(w * 32 + 16 + col) * LPAD + quad * 8]);
#pragma unroll
        for (int fm = 0; fm < 4; ++fm) {
            short8 a = *(const short8*)(&Asl[(fm * 16 + col) * LPAD + quad * 8]);
            acc[fm][0] = __builtin_amdgcn_mfma_f32_16x16x32_bf16(a, bf0, acc[fm][0], 0, 0, 0);
            acc[fm][1] = __builtin_amdgcn_mfma_f32_16x16x32_bf16(a, bf1, acc[fm][1], 0, 0, 0);
        }
        __syncthreads();
    }

    // epilogue: U/V bf16 [b][n][384]
    const int jbase = j0 + w * 32;
#pragma unroll
    for (int fn = 0; fn < 2; ++fn) {
        int j = jbase + fn * 16 + col;
        short* dst; int jj;
        if (j < CO) { dst = U; jj = j; } else { dst = V; jj = j - CO; }
#pragma unroll
        for (int fm = 0; fm < 4; ++fm) {
#pragma unroll
            for (int r = 0; r < 4; ++r) {
                int n = n0 + fm * 16 + quad * 4 + r;
                dst[((size_t)(b * Nn + n)) * CO + jj] = f2bf(acc[fm][fn][r]);
            }
        }
    }
}

// ---------------- gather + max + bias + relu, coalesced writes ----------------
// block: (32-node tile, batch via bid&7 for XCD L2 affinity), 384 threads.
__global__ __launch_bounds__(384) void gather_max(const int* __restrict__ ei,
                                                  const short* __restrict__ U,
                                                  const short* __restrict__ V,
                                                  const void* __restrict__ bias_,
                                                  void* __restrict__ out_,
                                                  const int* __restrict__ flags) {
    __shared__ float sm[32][385];   // [node][channel], +1 pad: conflict-free column reads
    __shared__ int si0[32][Kk];
    __shared__ int si1[32][Kk];

    const int fp32 = flags[0];
    const int is64 = flags[1];
    const int bid = blockIdx.x;
    const int b  = bid & 7;          // same-b blocks land on same XCD (round-robin heuristic)
    const int n0 = (bid >> 3) * 32;
    const int tid = threadIdx.x;

    for (int s = tid; s < 32 * 2 * Kk; s += 384) {
        int ln = s / (2 * Kk);
        int slot = s - ln * (2 * Kk);
        int n = n0 + ln;
        size_t pos; int* dstp;
        if (slot < Kk) { pos = ((size_t)b * Nn + n) * Kk + slot;              dstp = &si0[ln][slot]; }
        else           { pos = ((size_t)(Bb + b) * Nn + n) * Kk + (slot - Kk); dstp = &si1[ln][slot - Kk]; }
        int v = is64 ? ei[2 * pos] : ei[pos];
        *dstp = (v < 0) ? 0 : (v >= Nn ? Nn - 1 : v);
    }
    __syncthreads();

    const int p    = tid % 192;      // channel pair: o = 2p, 2p+1
    const int half = tid / 192;      // node half: 0 -> ln 0..15, 1 -> ln 16..31
    const unsigned short* Ub = (const unsigned short*)U + (size_t)b * Nn * CO;
    const unsigned short* Vb = (const unsigned short*)V + (size_t)b * Nn * CO;

    float b0, b1;
    if (fp32) {
        b0 = ((const float*)bias_)[2 * p];
        b1 = ((const float*)bias_)[2 * p + 1];
    } else {
        b0 = bf2f(((const unsigned short*)bias_)[2 * p]);
        b1 = bf2f(((const unsigned short*)bias_)[2 * p + 1]);
    }

    for (int ln = half * 16; ln < half * 16 + 16; ++ln) {
        float m0 = -INFINITY, m1 = -INFINITY;
#pragma unroll
        for (int k = 0; k < Kk; ++k) {
            unsigned int uu = *(const unsigned int*)(Ub + (size_t)si1[ln][k] * CO + 2 * p);
            unsigned int vv = *(const unsigned int*)(Vb + (size_t)si0[ln][k] * CO + 2 * p);
            m0 = fmaxf(m0, bf2f(uu & 0xffffu) + bf2f(vv & 0xffffu));
            m1 = fmaxf(m1, bf2f(uu >> 16) + bf2f(vv >> 16));
        }
        sm[ln][2 * p]     = fmaxf(m0 + b0, 0.0f);
        sm[ln][2 * p + 1] = fmaxf(m1 + b1, 0.0f);
    }
    __syncthreads();

    // transposed write: group g (12 groups of 32 lanes) covers rows o=g*32..g*32+31;
    // lane l writes n0+l -> 32 consecutive elements per row segment (coalesced).
    const int g = tid >> 5, l = tid & 31;
    if (fp32) {
        float* op = (float*)out_;
#pragma unroll
        for (int oo = 0; oo < 32; ++oo) {
            int o = g * 32 + oo;
            op[((size_t)b * CO + o) * Nn + n0 + l] = sm[l][o];
        }
    } else {
        __hip_bfloat16* op = (__hip_bfloat16*)out_;
#pragma unroll
        for (int oo = 0; oo < 32; ++oo) {
            int o = g * 32 + oo;
            op[((size_t)b * CO + o) * Nn + n0 + l] = __float2bfloat16(sm[l][o]);
        }
    }
}

extern "C" void kernel_launch(void* const* d_in, const int* in_sizes, int n_in,
                              void* d_out, int out_size, void* d_ws, size_t ws_size,
                              hipStream_t stream) {
    const void* x  = d_in[0];
    const int*  ei = (const int*)d_in[1];
    const void* W  = d_in[2];
    const void* bs = d_in[3];

    char* ws = (char*)d_ws;
    int*   flags = (int*)ws;                         // 64 B
    short* A_Tb  = (short*)(ws + 1024);              // 768*192*2 = 294,912 B
    short* U     = (short*)(ws + (1u << 20));        // 19,267,584 B
    short* V     = U + (size_t)Bb * Nn * CO;         // 19,267,584 B

    detect<<<1, 256, 0, stream>>>((const unsigned short*)x, ei, flags);

    prep_AT<<<(JTOT * Cc + 255) / 256, 256, 0, stream>>>(W, A_Tb, flags);

    dim3 g1(Nn / MT, JTOT / NT, Bb);   // (49, 6, 8)
    gemm_mfma<<<g1, 256, 0, stream>>>(x, A_Tb, U, V, flags);

    gather_max<<<(Nn / 32) * Bb, 384, 0, stream>>>(ei, U, V, bs, d_out, flags);
}

// Round 5
// 140.486 us; speedup vs baseline: 2.4122x; 1.3144x over previous
//
#include <hip/hip_runtime.h>
#include <hip/hip_bf16.h>

// B=8, C=192, N=3136, K=9, COUT=384.
// out[b,o,n] = relu( bias[o] + max_k( u[b,i1,o] + v[b,i0,o] ) )
//   u = (W1-W2)·xs,  v = W2·xs   (per-node GEMMs; 9x less compute than per-edge)
// Dtype-adaptive (1-wave runtime detect): fp32-vs-bf16 floats, int64-vs-int32 indices.
// ws: flags @0 | A_Tb bf16 [j=768][c=192] @1KB (295KB) | U bf16 @1MB | V bf16 (~39.6MB total)

#define Bb   8
#define Cc   192
#define Nn   3136
#define Kk   9
#define CO   384
#define TWOC 384
#define JTOT 768

typedef short  short8 __attribute__((ext_vector_type(8)));
typedef float  f32x4  __attribute__((ext_vector_type(4)));

__device__ __forceinline__ float bf2f(unsigned int u16) {
    union { unsigned int i; float f; } c;
    c.i = u16 << 16;
    return c.f;
}
__device__ __forceinline__ short f2bf(float f) {
    __hip_bfloat16 h = __float2bfloat16(f);
    short s; __builtin_memcpy(&s, &h, 2); return s;
}

// ---------------- detect input dtypes: one wave, 2 loads/lane ----------------
// fp32 test: bf16-exponent of even-position ushorts; N(0,1) bf16 never has e>=0x88
//            (|x|>=512), fp32 mantissa-low halves hit with p=0.47 -> P(miss)~2e-18.
// int64 test: odd int32 words all zero iff indices are int64 (values < 2^31).
__global__ __launch_bounds__(64) void detect(const unsigned short* __restrict__ xu,
                                             const int* __restrict__ ei,
                                             int* __restrict__ flags) {
    const int lane = threadIdx.x;
    unsigned int u = xu[2 * lane];                    // even positions, first 256 B
    int bige = (((u >> 7) & 0xFFu) >= 0x88u);
    unsigned long long bf = __ballot(bige);
    int oddnz = (ei[2 * lane + 1] != 0);
    unsigned long long bo = __ballot(oddnz);
    if (lane == 0) {
        flags[0] = (bf != 0ull) ? 1 : 0;   // floats are fp32
        flags[1] = (bo == 0ull) ? 1 : 0;   // indices are int64
    }
}

// ---------------- prep: A_Tb[j][c] bf16; j<384: W1-W2, j>=384: W2 ----------------
__global__ __launch_bounds__(256) void prep_AT(const void* __restrict__ W_,
                                               short* __restrict__ A_Tb,
                                               const int* __restrict__ flags) {
    const int fp32 = flags[0];
    int t = blockIdx.x * 256 + threadIdx.x;
    if (t >= JTOT * Cc) return;
    int j = t / Cc;
    int c = t - j * Cc;
    int row = (j < CO) ? j : (j - CO);
    float w1, w2;
    if (fp32) {
        const float* W = (const float*)W_;
        w1 = W[row * TWOC + c];  w2 = W[row * TWOC + Cc + c];
    } else {
        const unsigned short* W = (const unsigned short*)W_;
        w1 = bf2f(W[row * TWOC + c]);  w2 = bf2f(W[row * TWOC + Cc + c]);
    }
    A_Tb[t] = f2bf((j < CO) ? (w1 - w2) : w2);
}

// ---------------- MFMA GEMM: T[b][n][j] = sum_c xs[b][c][n] * A_T[c][j] ----------------
// tile 64(n) x 256(j), K-step 32; 4 waves: wave w covers j-range [w*64, w*64+64)
#define MT 64
#define NT 256
#define KT 32
#define LPAD 40   // LDS row stride in bf16 elems: 80B rows, 2-way bank alias = free

__global__ __launch_bounds__(256) void gemm_mfma(const void* __restrict__ x_,
                                                 const short* __restrict__ A_Tb,
                                                 short* __restrict__ U,
                                                 short* __restrict__ V,
                                                 const int* __restrict__ flags) {
    __shared__ short Asl[MT * LPAD];   // [n][c]  5,120 B
    __shared__ short Bsl[NT * LPAD];   // [j][c] 20,480 B

    const int fp32 = flags[0];
    const int n0 = blockIdx.x * MT;
    const int j0 = blockIdx.y * NT;
    const int b  = blockIdx.z;
    const int tid  = threadIdx.x;
    const int w    = tid >> 6;
    const int lane = tid & 63;
    const int col  = lane & 15;
    const int quad = lane >> 4;

    f32x4 acc[4][4];
#pragma unroll
    for (int i = 0; i < 4; ++i)
#pragma unroll
        for (int jf = 0; jf < 4; ++jf) acc[i][jf] = (f32x4)(0.0f);

    const int ac   = tid >> 3;   // c-index 0..31 for A staging
    const int aseg = tid & 7;    // n-segment (8 nodes)

    for (int c0 = 0; c0 < Cc; c0 += KT) {
        // stage A: xs[b][c][n] -> Asl[n][c]  (transpose in LDS)
        if (fp32) {
            const float* xb = (const float*)x_ + ((size_t)b * Cc + c0 + ac) * Nn + n0 + aseg * 8;
            float4 v0 = *(const float4*)xb;
            float4 v1 = *(const float4*)(xb + 4);
            int nb = aseg * 8;
            Asl[(nb + 0) * LPAD + ac] = f2bf(v0.x);
            Asl[(nb + 1) * LPAD + ac] = f2bf(v0.y);
            Asl[(nb + 2) * LPAD + ac] = f2bf(v0.z);
            Asl[(nb + 3) * LPAD + ac] = f2bf(v0.w);
            Asl[(nb + 4) * LPAD + ac] = f2bf(v1.x);
            Asl[(nb + 5) * LPAD + ac] = f2bf(v1.y);
            Asl[(nb + 6) * LPAD + ac] = f2bf(v1.z);
            Asl[(nb + 7) * LPAD + ac] = f2bf(v1.w);
        } else {
            const unsigned short* xb = (const unsigned short*)x_ + ((size_t)b * Cc + c0 + ac) * Nn + n0 + aseg * 8;
            ushort4 u0 = *(const ushort4*)xb;
            ushort4 u1 = *(const ushort4*)(xb + 4);
            int nb = aseg * 8;
            Asl[(nb + 0) * LPAD + ac] = (short)u0.x;
            Asl[(nb + 1) * LPAD + ac] = (short)u0.y;
            Asl[(nb + 2) * LPAD + ac] = (short)u0.z;
            Asl[(nb + 3) * LPAD + ac] = (short)u0.w;
            Asl[(nb + 4) * LPAD + ac] = (short)u1.x;
            Asl[(nb + 5) * LPAD + ac] = (short)u1.y;
            Asl[(nb + 6) * LPAD + ac] = (short)u1.z;
            Asl[(nb + 7) * LPAD + ac] = (short)u1.w;
        }
        // stage B: A_Tb[j][c] -> Bsl[j][c]  (straight 16B copies, j = tid)
        {
            const short8* src = (const short8*)(A_Tb + (size_t)(j0 + tid) * Cc + c0);
#pragma unroll
            for (int h = 0; h < 4; ++h)
                *(short8*)(&Bsl[tid * LPAD + h * 8]) = src[h];
        }
        __syncthreads();

        // A[m=lane&15][k=quad*8+i], B[k=quad*8+i][n=lane&15], D[row=quad*4+r][col=lane&15]
        short8 bf[4];
#pragma unroll
        for (int jf = 0; jf < 4; ++jf)
            bf[jf] = *(const short8*)(&Bsl[(w * 64 + jf * 16 + col) * LPAD + quad * 8]);
#pragma unroll
        for (int fm = 0; fm < 4; ++fm) {
            short8 a = *(const short8*)(&Asl[(fm * 16 + col) * LPAD + quad * 8]);
#pragma unroll
            for (int jf = 0; jf < 4; ++jf)
                acc[fm][jf] = __builtin_amdgcn_mfma_f32_16x16x32_bf16(a, bf[jf], acc[fm][jf], 0, 0, 0);
        }
        __syncthreads();
    }

    // epilogue: U/V bf16 [b][n][384]
    const int jbase = j0 + w * 64;
#pragma unroll
    for (int fn = 0; fn < 4; ++fn) {
        int j = jbase + fn * 16 + col;
        short* dst; int jj;
        if (j < CO) { dst = U; jj = j; } else { dst = V; jj = j - CO; }
#pragma unroll
        for (int fm = 0; fm < 4; ++fm) {
#pragma unroll
            for (int r = 0; r < 4; ++r) {
                int n = n0 + fm * 16 + quad * 4 + r;
                dst[((size_t)(b * Nn + n)) * CO + jj] = f2bf(acc[fm][fn][r]);
            }
        }
    }
}

// ---------------- gather + max + bias + relu, coalesced writes ----------------
__global__ __launch_bounds__(384) void gather_max(const int* __restrict__ ei,
                                                  const short* __restrict__ U,
                                                  const short* __restrict__ V,
                                                  const void* __restrict__ bias_,
                                                  void* __restrict__ out_,
                                                  const int* __restrict__ flags) {
    __shared__ float sm[32][385];   // [node][channel], +1 pad
    __shared__ int si0[32][Kk];
    __shared__ int si1[32][Kk];

    const int fp32 = flags[0];
    const int is64 = flags[1];
    const int bid = blockIdx.x;
    const int b  = bid & 7;          // same-b blocks share XCD L2 (round-robin heuristic)
    const int n0 = (bid >> 3) * 32;
    const int tid = threadIdx.x;

    for (int s = tid; s < 32 * 2 * Kk; s += 384) {
        int ln = s / (2 * Kk);
        int slot = s - ln * (2 * Kk);
        int n = n0 + ln;
        size_t pos; int* dstp;
        if (slot < Kk) { pos = ((size_t)b * Nn + n) * Kk + slot;              dstp = &si0[ln][slot]; }
        else           { pos = ((size_t)(Bb + b) * Nn + n) * Kk + (slot - Kk); dstp = &si1[ln][slot - Kk]; }
        int v = is64 ? ei[2 * pos] : ei[pos];
        *dstp = (v < 0) ? 0 : (v >= Nn ? Nn - 1 : v);
    }
    __syncthreads();

    const int p    = tid % 192;      // channel pair: o = 2p, 2p+1
    const int half = tid / 192;
    const unsigned short* Ub = (const unsigned short*)U + (size_t)b * Nn * CO;
    const unsigned short* Vb = (const unsigned short*)V + (size_t)b * Nn * CO;

    float b0, b1;
    if (fp32) {
        b0 = ((const float*)bias_)[2 * p];
        b1 = ((const float*)bias_)[2 * p + 1];
    } else {
        b0 = bf2f(((const unsigned short*)bias_)[2 * p]);
        b1 = bf2f(((const unsigned short*)bias_)[2 * p + 1]);
    }

    for (int ln = half * 16; ln < half * 16 + 16; ++ln) {
        float m0 = -INFINITY, m1 = -INFINITY;
#pragma unroll
        for (int k = 0; k < Kk; ++k) {
            unsigned int uu = *(const unsigned int*)(Ub + (size_t)si1[ln][k] * CO + 2 * p);
            unsigned int vv = *(const unsigned int*)(Vb + (size_t)si0[ln][k] * CO + 2 * p);
            m0 = fmaxf(m0, bf2f(uu & 0xffffu) + bf2f(vv & 0xffffu));
            m1 = fmaxf(m1, bf2f(uu >> 16) + bf2f(vv >> 16));
        }
        sm[ln][2 * p]     = fmaxf(m0 + b0, 0.0f);
        sm[ln][2 * p + 1] = fmaxf(m1 + b1, 0.0f);
    }
    __syncthreads();

    // transposed write: 12 groups of 32 lanes; lane l writes n0+l (coalesced 32-wide)
    const int g = tid >> 5, l = tid & 31;
    if (fp32) {
        float* op = (float*)out_;
#pragma unroll
        for (int oo = 0; oo < 32; ++oo) {
            int o = g * 32 + oo;
            op[((size_t)b * CO + o) * Nn + n0 + l] = sm[l][o];
        }
    } else {
        __hip_bfloat16* op = (__hip_bfloat16*)out_;
#pragma unroll
        for (int oo = 0; oo < 32; ++oo) {
            int o = g * 32 + oo;
            op[((size_t)b * CO + o) * Nn + n0 + l] = __float2bfloat16(sm[l][o]);
        }
    }
}

extern "C" void kernel_launch(void* const* d_in, const int* in_sizes, int n_in,
                              void* d_out, int out_size, void* d_ws, size_t ws_size,
                              hipStream_t stream) {
    const void* x  = d_in[0];
    const int*  ei = (const int*)d_in[1];
    const void* W  = d_in[2];
    const void* bs = d_in[3];

    char* ws = (char*)d_ws;
    int*   flags = (int*)ws;                         // 64 B
    short* A_Tb  = (short*)(ws + 1024);              // 294,912 B
    short* U     = (short*)(ws + (1u << 20));        // 19,267,584 B
    short* V     = U + (size_t)Bb * Nn * CO;         // 19,267,584 B

    detect<<<1, 64, 0, stream>>>((const unsigned short*)x, ei, flags);

    prep_AT<<<(JTOT * Cc + 255) / 256, 256, 0, stream>>>(W, A_Tb, flags);

    dim3 g1(Nn / MT, JTOT / NT, Bb);   // (49, 3, 8)
    gemm_mfma<<<g1, 256, 0, stream>>>(x, A_Tb, U, V, flags);

    gather_max<<<(Nn / 32) * Bb, 384, 0, stream>>>(ei, U, V, bs, d_out, flags);
}